// Round 1
// baseline (2031.748 us; speedup 1.0000x reference)
//
#include <hip/hip_runtime.h>

#define NN 100000
#define NE 1600000
#define NG 64
#define EPS 1e-5f

// ---------- helpers ----------
__device__ __forceinline__ int wave_gid() {
  // wave-uniform global wave id (readfirstlane forces uniformity for the compiler)
  return __builtin_amdgcn_readfirstlane((int)((blockIdx.x * blockDim.x + threadIdx.x) >> 6));
}

__device__ __forceinline__ float bcast(float v, int l) {
  return __uint_as_float(__builtin_amdgcn_readlane(__float_as_uint(v), l));
}

// order-preserving float->uint map (monotonic): larger float => larger uint
__device__ __forceinline__ unsigned ord_of_float(float f) {
  unsigned b = __float_as_uint(f);
  return (b & 0x80000000u) ? ~b : (b | 0x80000000u);
}

// ---------- K0: x = h @ fe_w + fe_b   (N x 4 @ 4 x 64) ----------
__global__ void k_init_x(const float* __restrict__ h, const float* __restrict__ few,
                         const float* __restrict__ feb, float* __restrict__ x) {
  int lane = threadIdx.x & 63;
  int wg = wave_gid();
  int nw = (gridDim.x * blockDim.x) >> 6;
  float w0 = few[0 * 64 + lane], w1 = few[1 * 64 + lane];
  float w2 = few[2 * 64 + lane], w3 = few[3 * 64 + lane];
  float b = feb[lane];
  for (int n = wg; n < NN; n += nw) {
    float4 hv = *(const float4*)(h + (size_t)n * 4);
    x[(size_t)n * 64 + lane] = fmaf(hv.x, w0, fmaf(hv.y, w1, fmaf(hv.z, w2, fmaf(hv.w, w3, b))));
  }
}

// ---------- K1: delta MLP + q = pos - delta ----------
__global__ void k_delta_q(const float* __restrict__ x, const float* __restrict__ pos,
                          const float* __restrict__ hw1, const float* __restrict__ hb1,
                          const float* __restrict__ hw2, const float* __restrict__ hb2,
                          float* __restrict__ q) {
  int lane = threadIdx.x & 63;
  int wg = wave_gid();
  int nw = (gridDim.x * blockDim.x) >> 6;
  float wc[64];
#pragma unroll
  for (int d = 0; d < 64; ++d) wc[d] = hw1[d * 64 + lane];
  float b1 = hb1[lane];
  float w20 = hw2[lane * 3 + 0], w21 = hw2[lane * 3 + 1], w22 = hw2[lane * 3 + 2];
  float b20 = hb2[0], b21 = hb2[1], b22 = hb2[2];
  for (int n = wg; n < NN; n += nw) {
    const float4* xr = (const float4*)(x + (size_t)n * 64);
    float a0 = 0.f, a1 = 0.f, a2 = 0.f, a3 = 0.f;
#pragma unroll
    for (int k = 0; k < 16; ++k) {
      float4 v = xr[k];
      a0 = fmaf(v.x, wc[4 * k + 0], a0);
      a1 = fmaf(v.y, wc[4 * k + 1], a1);
      a2 = fmaf(v.z, wc[4 * k + 2], a2);
      a3 = fmaf(v.w, wc[4 * k + 3], a3);
    }
    float t = fmaxf((a0 + a1) + (a2 + a3) + b1, 0.f);
    float p0 = t * w20, p1 = t * w21, p2 = t * w22;
#pragma unroll
    for (int off = 32; off; off >>= 1) {
      p0 += __shfl_xor(p0, off);
      p1 += __shfl_xor(p1, off);
      p2 += __shfl_xor(p2, off);
    }
    if (lane < 3) {
      float dc = (lane == 0) ? (p0 + b20) : ((lane == 1) ? (p1 + b21) : (p2 + b22));
      q[(size_t)n * 4 + lane] = pos[(size_t)n * 3 + lane] - dc;
    }
  }
}

// ---------- K2: xa = x @ fw1[3:,:] + fb1 ; agg init ----------
__global__ void k_xa(const float* __restrict__ x, const float* __restrict__ fw1,
                     const float* __restrict__ fb1, float* __restrict__ xa,
                     unsigned* __restrict__ agg) {
  int lane = threadIdx.x & 63;
  int wg = wave_gid();
  int nw = (gridDim.x * blockDim.x) >> 6;
  float wc[64];
#pragma unroll
  for (int d = 0; d < 64; ++d) wc[d] = fw1[(3 + d) * 64 + lane];
  float b = fb1[lane];
  for (int n = wg; n < NN; n += nw) {
    const float4* xr = (const float4*)(x + (size_t)n * 64);
    float a0 = 0.f, a1 = 0.f, a2 = 0.f, a3 = 0.f;
#pragma unroll
    for (int k = 0; k < 16; ++k) {
      float4 v = xr[k];
      a0 = fmaf(v.x, wc[4 * k + 0], a0);
      a1 = fmaf(v.y, wc[4 * k + 1], a1);
      a2 = fmaf(v.z, wc[4 * k + 2], a2);
      a3 = fmaf(v.w, wc[4 * k + 3], a3);
    }
    xa[(size_t)n * 64 + lane] = (a0 + a1) + (a2 + a3) + b;
    agg[(size_t)n * 64 + lane] = 0u;  // ord(-inf-ish): smaller than any real float's code
  }
}

// ---------- K3: edge kernel (the hot one) ----------
__global__ void k_edge(const float* __restrict__ xa, const float* __restrict__ pos,
                       const float* __restrict__ q, const int* __restrict__ ei,
                       const float* __restrict__ fw1, const float* __restrict__ fb2_,
                       const float* __restrict__ fw2, unsigned* __restrict__ agg) {
  int lane = threadIdx.x & 63;
  int wg = wave_gid();
  int nw = (gridDim.x * blockDim.x) >> 6;
  float w2c[64];
#pragma unroll
  for (int d = 0; d < 64; ++d) w2c[d] = fw2[d * 64 + lane];
  float w10 = fw1[0 * 64 + lane], w11 = fw1[1 * 64 + lane], w12 = fw1[2 * 64 + lane];
  float bl = fb2_[lane];
  for (int e = wg; e < NE; e += nw) {
    int src = ei[e];
    int dst = ei[NE + e];
    float4 qd = *(const float4*)(q + (size_t)dst * 4);
    float rx = pos[(size_t)src * 3 + 0] - qd.x;
    float ry = pos[(size_t)src * 3 + 1] - qd.y;
    float rz = pos[(size_t)src * 3 + 2] - qd.z;
    float hh = xa[(size_t)src * 64 + lane];
    hh = fmaxf(fmaf(rx, w10, fmaf(ry, w11, fmaf(rz, w12, hh))), 0.f);
    float m0 = bl, m1 = 0.f, m2 = 0.f, m3 = 0.f;
#pragma unroll
    for (int k = 0; k < 16; ++k) {
      m0 = fmaf(bcast(hh, 4 * k + 0), w2c[4 * k + 0], m0);
      m1 = fmaf(bcast(hh, 4 * k + 1), w2c[4 * k + 1], m1);
      m2 = fmaf(bcast(hh, 4 * k + 2), w2c[4 * k + 2], m2);
      m3 = fmaf(bcast(hh, 4 * k + 3), w2c[4 * k + 3], m3);
    }
    float msg = (m0 + m1) + (m2 + m3);
    unsigned u = ord_of_float(msg);
    unsigned* ap = agg + (size_t)dst * 64 + lane;
    // monotonic filter: stale reads only cause redundant atomics, never wrong skips
    if (u > *ap) atomicMax(ap, u);
  }
}

// ---------- K4: g = relu(agg @ gw1 + gb1), BN partial sums ----------
__global__ void k_g_bn(const unsigned* __restrict__ agg, const float* __restrict__ gw1,
                       const float* __restrict__ gb1, float* __restrict__ g,
                       float* __restrict__ bnp) {
  __shared__ float2 red[4][64];
  int lane = threadIdx.x & 63;
  int wid = threadIdx.x >> 6;
  int wg = wave_gid();
  int nw = (gridDim.x * blockDim.x) >> 6;
  float wc[64];
#pragma unroll
  for (int d = 0; d < 64; ++d) wc[d] = gw1[d * 64 + lane];
  float b = gb1[lane];
  float s = 0.f, ss = 0.f;
  for (int n = wg; n < NN; n += nw) {
    unsigned u = agg[(size_t)n * 64 + lane];
    unsigned fb = (u & 0x80000000u) ? (u & 0x7fffffffu) : ~u;
    float a = (u == 0u) ? 0.f : __uint_as_float(fb);  // empty segment -> 0
    float a0 = 0.f, a1 = 0.f, a2 = 0.f, a3 = 0.f;
#pragma unroll
    for (int k = 0; k < 16; ++k) {
      a0 = fmaf(bcast(a, 4 * k + 0), wc[4 * k + 0], a0);
      a1 = fmaf(bcast(a, 4 * k + 1), wc[4 * k + 1], a1);
      a2 = fmaf(bcast(a, 4 * k + 2), wc[4 * k + 2], a2);
      a3 = fmaf(bcast(a, 4 * k + 3), wc[4 * k + 3], a3);
    }
    float gv = fmaxf((a0 + a1) + (a2 + a3) + b, 0.f);
    g[(size_t)n * 64 + lane] = gv;
    s += gv;
    ss += gv * gv;
  }
  red[wid][lane] = make_float2(s, ss);
  __syncthreads();
  if (wid == 0) {
    float2 r0 = red[0][lane], r1 = red[1][lane], r2 = red[2][lane], r3 = red[3][lane];
    bnp[(size_t)blockIdx.x * 128 + lane] = r0.x + r1.x + r2.x + r3.x;
    bnp[(size_t)blockIdx.x * 128 + 64 + lane] = r0.y + r1.y + r2.y + r3.y;
  }
}

// ---------- K5: finalize BN, fold into W2', b2' ----------
__global__ void k_bn_final(const float* __restrict__ bnp, const float* __restrict__ gm,
                           const float* __restrict__ bt, const float* __restrict__ gw2,
                           const float* __restrict__ gb2, float* __restrict__ w2p,
                           float* __restrict__ b2p, int nblk) {
  __shared__ float sums[128];
  __shared__ float sc[64], sh[64];
  int t = threadIdx.x;  // 128 threads
  int c = t & 63;
  int kind = t >> 6;
  float acc = 0.f;
  for (int bId = 0; bId < nblk; ++bId) acc += bnp[(size_t)bId * 128 + kind * 64 + c];
  sums[t] = acc;
  __syncthreads();
  if (t < 64) {
    float mean = sums[t] * (1.f / (float)NN);
    float var = sums[64 + t] * (1.f / (float)NN) - mean * mean;
    float scale = gm[t] * rsqrtf(var + EPS);
    sc[t] = scale;
    sh[t] = bt[t] - mean * scale;
  }
  __syncthreads();
  for (int i = t; i < 4096; i += 128) {
    int d = i >> 6;
    w2p[i] = sc[d] * gw2[i];
  }
  if (t < 64) {
    float acc2 = gb2[t];
    for (int d = 0; d < 64; ++d) acc2 = fmaf(sh[d], gw2[d * 64 + t], acc2);
    b2p[t] = acc2;
  }
}

// ---------- K6: x += g @ W2' + b2' ----------
__global__ void k_update(const float* __restrict__ g, const float* __restrict__ w2p,
                         const float* __restrict__ b2p, float* __restrict__ x) {
  int lane = threadIdx.x & 63;
  int wg = wave_gid();
  int nw = (gridDim.x * blockDim.x) >> 6;
  float wc[64];
#pragma unroll
  for (int d = 0; d < 64; ++d) wc[d] = w2p[d * 64 + lane];
  float b = b2p[lane];
  for (int n = wg; n < NN; n += nw) {
    const float4* gr = (const float4*)(g + (size_t)n * 64);
    float a0 = 0.f, a1 = 0.f, a2 = 0.f, a3 = 0.f;
#pragma unroll
    for (int k = 0; k < 16; ++k) {
      float4 v = gr[k];
      a0 = fmaf(v.x, wc[4 * k + 0], a0);
      a1 = fmaf(v.y, wc[4 * k + 1], a1);
      a2 = fmaf(v.z, wc[4 * k + 2], a2);
      a3 = fmaf(v.w, wc[4 * k + 3], a3);
    }
    size_t idx = (size_t)n * 64 + lane;
    x[idx] = x[idx] + (a0 + a1) + (a2 + a3) + b;
  }
}

// ---------- K7: global mean pool (batch is sorted) ----------
__global__ void k_pool(const float* __restrict__ x, const int* __restrict__ batch,
                       float* __restrict__ pooled) {
  int lane = threadIdx.x & 63;
  int g = wave_gid();  // one wave per graph
  if (g >= NG) return;
  int a = 0, b = NN;
  while (a < b) {
    int m = (a + b) >> 1;
    if (batch[m] < g) a = m + 1; else b = m;
  }
  int s = a;
  b = NN;
  while (a < b) {
    int m = (a + b) >> 1;
    if (batch[m] < g + 1) a = m + 1; else b = m;
  }
  int e = a;
  float acc = 0.f;
  for (int n = s; n < e; ++n) acc += x[(size_t)n * 64 + lane];
  float cnt = (float)(e - s);
  pooled[(size_t)g * 64 + lane] = acc / fmaxf(cnt, 1.f);
}

// ---------- K8: readout MLP (64 graphs -> 16 outputs) ----------
__global__ void k_readout(const float* __restrict__ pooled, const float* __restrict__ w1,
                          const float* __restrict__ b1, const float* __restrict__ w2,
                          const float* __restrict__ b2, float* __restrict__ out) {
  __shared__ float hs[64];
  int lane = threadIdx.x;  // 64 threads, 1 block per graph
  int g = blockIdx.x;
  float wc[64];
#pragma unroll
  for (int d = 0; d < 64; ++d) wc[d] = w1[d * 64 + lane];
  const float4* pr = (const float4*)(pooled + (size_t)g * 64);
  float a0 = 0.f, a1 = 0.f, a2 = 0.f, a3 = 0.f;
#pragma unroll
  for (int k = 0; k < 16; ++k) {
    float4 v = pr[k];
    a0 = fmaf(v.x, wc[4 * k + 0], a0);
    a1 = fmaf(v.y, wc[4 * k + 1], a1);
    a2 = fmaf(v.z, wc[4 * k + 2], a2);
    a3 = fmaf(v.w, wc[4 * k + 3], a3);
  }
  hs[lane] = fmaxf((a0 + a1) + (a2 + a3) + b1[lane], 0.f);
  __syncthreads();
  if (lane < 16) {
    float acc = b2[lane];
#pragma unroll
    for (int l = 0; l < 64; ++l) acc = fmaf(hs[l], w2[l * 16 + lane], acc);
    out[(size_t)g * 16 + lane] = acc;
  }
}

// ---------- host ----------
extern "C" void kernel_launch(void* const* d_in, const int* in_sizes, int n_in,
                              void* d_out, int out_size, void* d_ws, size_t ws_size,
                              hipStream_t stream) {
  const float* h = (const float*)d_in[0];
  const float* pos = (const float*)d_in[1];
  const int* ei = (const int*)d_in[2];
  const int* batch = (const int*)d_in[3];
  const float* fe_w = (const float*)d_in[4];
  const float* fe_b = (const float*)d_in[5];
  const float* ro_w1 = (const float*)d_in[34];
  const float* ro_b1 = (const float*)d_in[35];
  const float* ro_w2 = (const float*)d_in[36];
  const float* ro_b2 = (const float*)d_in[37];
  float* out = (float*)d_out;

  char* ws = (char*)d_ws;
  const size_t SZ_ROW = (size_t)NN * 64 * sizeof(float);  // 25.6 MB
  float* x = (float*)(ws); ws += SZ_ROW;
  float* xa = (float*)(ws); ws += SZ_ROW;                 // reused as g after edge phase
  unsigned* agg = (unsigned*)(ws); ws += SZ_ROW;
  float* q = (float*)(ws); ws += (size_t)NN * 4 * sizeof(float);
  const int NBLK_BN = 256;
  float* bnp = (float*)(ws); ws += (size_t)NBLK_BN * 128 * sizeof(float);
  float* w2p = (float*)(ws); ws += 4096 * sizeof(float);
  float* b2p = (float*)(ws); ws += 256;
  float* pooled = (float*)(ws); ws += 4096 * sizeof(float);

  const int NB_NODE = 512;   // node-level kernels: 2048 waves
  const int NB_EDGE = 4096;  // edge kernel: 16384 waves

  k_init_x<<<NB_NODE, 256, 0, stream>>>(h, fe_w, fe_b, x);

  for (int layer = 0; layer < 2; ++layer) {
    int base = (layer == 0) ? 6 : 20;
    const float* hw1 = (const float*)d_in[base + 0];
    const float* hb1 = (const float*)d_in[base + 1];
    const float* hw2 = (const float*)d_in[base + 2];
    const float* hb2 = (const float*)d_in[base + 3];
    const float* fw1 = (const float*)d_in[base + 4];
    const float* fb1 = (const float*)d_in[base + 5];
    const float* fw2 = (const float*)d_in[base + 6];
    const float* fb2 = (const float*)d_in[base + 7];
    const float* gw1 = (const float*)d_in[base + 8];
    const float* gb1 = (const float*)d_in[base + 9];
    const float* ggm = (const float*)d_in[base + 10];
    const float* gbt = (const float*)d_in[base + 11];
    const float* gw2 = (const float*)d_in[base + 12];
    const float* gb2 = (const float*)d_in[base + 13];

    k_delta_q<<<NB_NODE, 256, 0, stream>>>(x, pos, hw1, hb1, hw2, hb2, q);
    k_xa<<<NB_NODE, 256, 0, stream>>>(x, fw1, fb1, xa, agg);
    k_edge<<<NB_EDGE, 256, 0, stream>>>(xa, pos, q, ei, fw1, fb2, fw2, agg);
    float* g = xa;  // xa dead after k_edge; reuse as g
    k_g_bn<<<NBLK_BN, 256, 0, stream>>>(agg, gw1, gb1, g, bnp);
    k_bn_final<<<1, 128, 0, stream>>>(bnp, ggm, gbt, gw2, gb2, w2p, b2p, NBLK_BN);
    k_update<<<NB_NODE, 256, 0, stream>>>(g, w2p, b2p, x);
  }

  k_pool<<<16, 256, 0, stream>>>(x, batch, pooled);
  k_readout<<<NG, 64, 0, stream>>>(pooled, ro_w1, ro_b1, ro_w2, ro_b2, out);
}

// Round 4
// 1585.586 us; speedup vs baseline: 1.2814x; 1.2814x over previous
//
#include <hip/hip_runtime.h>

#define NN 100000
#define NE 1600000
#define NG 64
#define EPS 1e-5f

// ---------- macro machinery: 16 named float4 regs = one 64-row weight column ----------
// Named scalars cannot be demoted to scratch (rule #20) — fix for the round-1
// pathology (k_delta_q VGPR=44 => wc[64] array spilled to local memory).
// Register names are wr<i>_ to avoid collisions with any kernel locals.
#define FOR16(M) M(0) M(1) M(2) M(3) M(4) M(5) M(6) M(7) M(8) M(9) M(10) M(11) M(12) M(13) M(14) M(15)
#define WDECL(i) float4 wr##i##_;
// load column `lane` of rows [RB+4i .. RB+4i+3] of row-major [*,64] matrix P
#define LDW(i, RB, P) \
  wr##i##_.x = (P)[((RB) + 4 * i + 0) * 64 + lane]; \
  wr##i##_.y = (P)[((RB) + 4 * i + 1) * 64 + lane]; \
  wr##i##_.z = (P)[((RB) + 4 * i + 2) * 64 + lane]; \
  wr##i##_.w = (P)[((RB) + 4 * i + 3) * 64 + lane];
// dot with a row held as float4* xr (same values in all lanes)
#define DOTR(i) { float4 v = xr[i]; \
  a0 = fmaf(v.x, wr##i##_.x, a0); a1 = fmaf(v.y, wr##i##_.y, a1); \
  a2 = fmaf(v.z, wr##i##_.z, a2); a3 = fmaf(v.w, wr##i##_.w, a3); }
// dot with a value lane-distributed in variable SRC (lane d holds elem d), via readlane bcast
#define DOTB(i, SRC) { \
  a0 = fmaf(bcast(SRC, 4 * i + 0), wr##i##_.x, a0); \
  a1 = fmaf(bcast(SRC, 4 * i + 1), wr##i##_.y, a1); \
  a2 = fmaf(bcast(SRC, 4 * i + 2), wr##i##_.z, a2); \
  a3 = fmaf(bcast(SRC, 4 * i + 3), wr##i##_.w, a3); }

// ---------- helpers ----------
__device__ __forceinline__ int wave_gid() {
  return __builtin_amdgcn_readfirstlane((int)((blockIdx.x * blockDim.x + threadIdx.x) >> 6));
}

__device__ __forceinline__ float bcast(float v, int l) {
  return __uint_as_float(__builtin_amdgcn_readlane(__float_as_uint(v), l));
}

// order-preserving float->uint map (monotonic): larger float => larger uint
__device__ __forceinline__ unsigned ord_of_float(float f) {
  unsigned b = __float_as_uint(f);
  return (b & 0x80000000u) ? ~b : (b | 0x80000000u);
}

// ---------- K0: x = h @ fe_w + fe_b   (N x 4 @ 4 x 64) ----------
__global__ void k_init_x(const float* __restrict__ h, const float* __restrict__ few,
                         const float* __restrict__ feb, float* __restrict__ x) {
  int lane = threadIdx.x & 63;
  int wg = wave_gid();
  int nw = (gridDim.x * blockDim.x) >> 6;
  float c0 = few[0 * 64 + lane], c1 = few[1 * 64 + lane];
  float c2 = few[2 * 64 + lane], c3 = few[3 * 64 + lane];
  float b = feb[lane];
  for (int n = wg; n < NN; n += nw) {
    float4 hv = *(const float4*)(h + (size_t)n * 4);
    x[(size_t)n * 64 + lane] = fmaf(hv.x, c0, fmaf(hv.y, c1, fmaf(hv.z, c2, fmaf(hv.w, c3, b))));
  }
}

// ---------- K1: delta MLP + q = pos - delta ----------
__global__ void k_delta_q(const float* __restrict__ x, const float* __restrict__ pos,
                          const float* __restrict__ hw1, const float* __restrict__ hb1,
                          const float* __restrict__ hw2, const float* __restrict__ hb2,
                          float* __restrict__ q) {
  int lane = threadIdx.x & 63;
  int wg = wave_gid();
  int nw = (gridDim.x * blockDim.x) >> 6;
  FOR16(WDECL)
#define LD(i) LDW(i, 0, hw1)
  FOR16(LD)
#undef LD
  float b1 = hb1[lane];
  float u0 = hw2[lane * 3 + 0], u1 = hw2[lane * 3 + 1], u2 = hw2[lane * 3 + 2];
  float b20 = hb2[0], b21 = hb2[1], b22 = hb2[2];
  for (int n = wg; n < NN; n += nw) {
    const float4* xr = (const float4*)(x + (size_t)n * 64);
    float a0 = 0.f, a1 = 0.f, a2 = 0.f, a3 = 0.f;
    FOR16(DOTR)
    float t = fmaxf((a0 + a1) + (a2 + a3) + b1, 0.f);
    float p0 = t * u0, p1 = t * u1, p2 = t * u2;
#pragma unroll
    for (int off = 32; off; off >>= 1) {
      p0 += __shfl_xor(p0, off);
      p1 += __shfl_xor(p1, off);
      p2 += __shfl_xor(p2, off);
    }
    if (lane < 3) {
      float dc = (lane == 0) ? (p0 + b20) : ((lane == 1) ? (p1 + b21) : (p2 + b22));
      q[(size_t)n * 4 + lane] = pos[(size_t)n * 3 + lane] - dc;
    }
  }
}

// ---------- K2: xa = x @ fw1[3:,:] + fb1 ; agg init ----------
__global__ void k_xa(const float* __restrict__ x, const float* __restrict__ fw1,
                     const float* __restrict__ fb1, float* __restrict__ xa,
                     unsigned* __restrict__ agg) {
  int lane = threadIdx.x & 63;
  int wg = wave_gid();
  int nw = (gridDim.x * blockDim.x) >> 6;
  FOR16(WDECL)
#define LD(i) LDW(i, 3, fw1)
  FOR16(LD)
#undef LD
  float b = fb1[lane];
  for (int n = wg; n < NN; n += nw) {
    const float4* xr = (const float4*)(x + (size_t)n * 64);
    float a0 = 0.f, a1 = 0.f, a2 = 0.f, a3 = 0.f;
    FOR16(DOTR)
    xa[(size_t)n * 64 + lane] = (a0 + a1) + (a2 + a3) + b;
    agg[(size_t)n * 64 + lane] = 0u;  // ord code below any real float's code
  }
}

// ---------- K3: edge kernel (the hot one) ----------
__global__ void k_edge(const float* __restrict__ xa, const float* __restrict__ pos,
                       const float* __restrict__ q, const int* __restrict__ ei,
                       const float* __restrict__ fw1, const float* __restrict__ fb2_,
                       const float* __restrict__ fw2, unsigned* __restrict__ agg) {
  int lane = threadIdx.x & 63;
  int wg = wave_gid();
  int nw = (gridDim.x * blockDim.x) >> 6;
  FOR16(WDECL)
#define LD(i) LDW(i, 0, fw2)
  FOR16(LD)
#undef LD
  float pw0 = fw1[0 * 64 + lane], pw1 = fw1[1 * 64 + lane], pw2 = fw1[2 * 64 + lane];
  float bl = fb2_[lane];
  for (int e = wg; e < NE; e += nw) {
    int src = ei[e];
    int dst = ei[NE + e];
    float4 qd = *(const float4*)(q + (size_t)dst * 4);
    float rx = pos[(size_t)src * 3 + 0] - qd.x;
    float ry = pos[(size_t)src * 3 + 1] - qd.y;
    float rz = pos[(size_t)src * 3 + 2] - qd.z;
    float hh = xa[(size_t)src * 64 + lane];
    hh = fmaxf(fmaf(rx, pw0, fmaf(ry, pw1, fmaf(rz, pw2, hh))), 0.f);
    float a0 = bl, a1 = 0.f, a2 = 0.f, a3 = 0.f;
#define DB(i) DOTB(i, hh)
    FOR16(DB)
#undef DB
    float msg = (a0 + a1) + (a2 + a3);
    unsigned u = ord_of_float(msg);
    unsigned* ap = agg + (size_t)dst * 64 + lane;
    // monotonic filter: stale reads only cause redundant atomics, never wrong skips
    if (u > *ap) atomicMax(ap, u);
  }
}

// ---------- K4: g = relu(agg @ gw1 + gb1), BN partial sums ----------
__global__ void k_g_bn(const unsigned* __restrict__ agg, const float* __restrict__ gw1,
                       const float* __restrict__ gb1, float* __restrict__ g,
                       float* __restrict__ bnp) {
  __shared__ float2 red[4][64];
  int lane = threadIdx.x & 63;
  int wid = threadIdx.x >> 6;
  int wg = wave_gid();
  int nw = (gridDim.x * blockDim.x) >> 6;
  FOR16(WDECL)
#define LD(i) LDW(i, 0, gw1)
  FOR16(LD)
#undef LD
  float b = gb1[lane];
  float s = 0.f, ss = 0.f;
  for (int n = wg; n < NN; n += nw) {
    unsigned u = agg[(size_t)n * 64 + lane];
    unsigned fb = (u & 0x80000000u) ? (u & 0x7fffffffu) : ~u;
    float av = (u == 0u) ? 0.f : __uint_as_float(fb);  // empty segment -> 0
    float a0 = 0.f, a1 = 0.f, a2 = 0.f, a3 = 0.f;
#define DB(i) DOTB(i, av)
    FOR16(DB)
#undef DB
    float gv = fmaxf((a0 + a1) + (a2 + a3) + b, 0.f);
    g[(size_t)n * 64 + lane] = gv;
    s += gv;
    ss += gv * gv;
  }
  red[wid][lane] = make_float2(s, ss);
  __syncthreads();
  if (wid == 0) {
    float2 r0 = red[0][lane], r1 = red[1][lane], r2 = red[2][lane], r3 = red[3][lane];
    bnp[(size_t)blockIdx.x * 128 + lane] = r0.x + r1.x + r2.x + r3.x;
    bnp[(size_t)blockIdx.x * 128 + 64 + lane] = r0.y + r1.y + r2.y + r3.y;
  }
}

// ---------- K5: finalize BN, fold into W2', b2' ----------
__global__ void k_bn_final(const float* __restrict__ bnp, const float* __restrict__ gm,
                           const float* __restrict__ bt, const float* __restrict__ gw2,
                           const float* __restrict__ gb2, float* __restrict__ w2p,
                           float* __restrict__ b2p, int nblk) {
  __shared__ float sums[128];
  __shared__ float sc[64], sh[64];
  int t = threadIdx.x;  // 128 threads
  int c = t & 63;
  int kind = t >> 6;
  float acc = 0.f;
  for (int bId = 0; bId < nblk; ++bId) acc += bnp[(size_t)bId * 128 + kind * 64 + c];
  sums[t] = acc;
  __syncthreads();
  if (t < 64) {
    float mean = sums[t] * (1.f / (float)NN);
    float var = sums[64 + t] * (1.f / (float)NN) - mean * mean;
    float scale = gm[t] * rsqrtf(var + EPS);
    sc[t] = scale;
    sh[t] = bt[t] - mean * scale;
  }
  __syncthreads();
  for (int i = t; i < 4096; i += 128) {
    int d = i >> 6;
    w2p[i] = sc[d] * gw2[i];
  }
  if (t < 64) {
    float acc2 = gb2[t];
    for (int d = 0; d < 64; ++d) acc2 = fmaf(sh[d], gw2[d * 64 + t], acc2);
    b2p[t] = acc2;
  }
}

// ---------- K6: x += g @ W2' + b2' ----------
__global__ void k_update(const float* __restrict__ g, const float* __restrict__ w2p,
                         const float* __restrict__ b2p, float* __restrict__ x) {
  int lane = threadIdx.x & 63;
  int wg = wave_gid();
  int nw = (gridDim.x * blockDim.x) >> 6;
  FOR16(WDECL)
#define LD(i) LDW(i, 0, w2p)
  FOR16(LD)
#undef LD
  float b = b2p[lane];
  for (int n = wg; n < NN; n += nw) {
    const float4* xr = (const float4*)(g + (size_t)n * 64);
    float a0 = 0.f, a1 = 0.f, a2 = 0.f, a3 = 0.f;
    FOR16(DOTR)
    size_t idx = (size_t)n * 64 + lane;
    x[idx] = x[idx] + (a0 + a1) + (a2 + a3) + b;
  }
}

// ---------- K7: global mean pool (batch sorted) — one 8-wave block per graph ----------
__global__ void k_pool(const float* __restrict__ x, const int* __restrict__ batch,
                       float* __restrict__ pooled) {
  __shared__ float red[8][64];
  int lane = threadIdx.x & 63;
  int wid = threadIdx.x >> 6;  // 0..7
  int g = blockIdx.x;
  // binary search [s,e) of graph g in sorted batch (all threads redundantly)
  int a = 0, b = NN;
  while (a < b) {
    int m = (a + b) >> 1;
    if (batch[m] < g) a = m + 1; else b = m;
  }
  int s = a;
  b = NN;
  while (a < b) {
    int m = (a + b) >> 1;
    if (batch[m] < g + 1) a = m + 1; else b = m;
  }
  int e = a;
  float acc = 0.f;
  for (int n = s + wid; n < e; n += 8) acc += x[(size_t)n * 64 + lane];
  red[wid][lane] = acc;
  __syncthreads();
  if (wid == 0) {
    float t = 0.f;
#pragma unroll
    for (int w = 0; w < 8; ++w) t += red[w][lane];
    float cnt = (float)(e - s);
    pooled[(size_t)g * 64 + lane] = t / fmaxf(cnt, 1.f);
  }
}

// ---------- K8: readout MLP (64 graphs -> 16 outputs) ----------
__global__ void k_readout(const float* __restrict__ pooled, const float* __restrict__ w1,
                          const float* __restrict__ b1, const float* __restrict__ w2,
                          const float* __restrict__ b2, float* __restrict__ out) {
  __shared__ float hs[64];
  int lane = threadIdx.x;  // 64 threads, 1 block per graph
  int g = blockIdx.x;
  FOR16(WDECL)
#define LD(i) LDW(i, 0, w1)
  FOR16(LD)
#undef LD
  const float4* xr = (const float4*)(pooled + (size_t)g * 64);
  float a0 = 0.f, a1 = 0.f, a2 = 0.f, a3 = 0.f;
  FOR16(DOTR)
  hs[lane] = fmaxf((a0 + a1) + (a2 + a3) + b1[lane], 0.f);
  __syncthreads();
  if (lane < 16) {
    float acc = b2[lane];
#pragma unroll
    for (int l = 0; l < 64; ++l) acc = fmaf(hs[l], w2[l * 16 + lane], acc);
    out[(size_t)g * 16 + lane] = acc;
  }
}

// ---------- host ----------
extern "C" void kernel_launch(void* const* d_in, const int* in_sizes, int n_in,
                              void* d_out, int out_size, void* d_ws, size_t ws_size,
                              hipStream_t stream) {
  const float* h = (const float*)d_in[0];
  const float* pos = (const float*)d_in[1];
  const int* ei = (const int*)d_in[2];
  const int* batch = (const int*)d_in[3];
  const float* fe_w = (const float*)d_in[4];
  const float* fe_b = (const float*)d_in[5];
  const float* ro_w1 = (const float*)d_in[34];
  const float* ro_b1 = (const float*)d_in[35];
  const float* ro_w2 = (const float*)d_in[36];
  const float* ro_b2 = (const float*)d_in[37];
  float* out = (float*)d_out;

  char* ws = (char*)d_ws;
  const size_t SZ_ROW = (size_t)NN * 64 * sizeof(float);  // 25.6 MB
  float* x = (float*)(ws); ws += SZ_ROW;
  float* xa = (float*)(ws); ws += SZ_ROW;                 // reused as g after edge phase
  unsigned* agg = (unsigned*)(ws); ws += SZ_ROW;
  float* q = (float*)(ws); ws += (size_t)NN * 4 * sizeof(float);
  const int NBLK_BN = 256;
  float* bnp = (float*)(ws); ws += (size_t)NBLK_BN * 128 * sizeof(float);
  float* w2p = (float*)(ws); ws += 4096 * sizeof(float);
  float* b2p = (float*)(ws); ws += 256;
  float* pooled = (float*)(ws); ws += 4096 * sizeof(float);

  const int NB_NODE = 512;   // node-level kernels: 2048 waves
  const int NB_EDGE = 4096;  // edge kernel: 16384 waves

  k_init_x<<<NB_NODE, 256, 0, stream>>>(h, fe_w, fe_b, x);

  for (int layer = 0; layer < 2; ++layer) {
    int base = (layer == 0) ? 6 : 20;
    const float* hw1 = (const float*)d_in[base + 0];
    const float* hb1 = (const float*)d_in[base + 1];
    const float* hw2 = (const float*)d_in[base + 2];
    const float* hb2 = (const float*)d_in[base + 3];
    const float* fw1 = (const float*)d_in[base + 4];
    const float* fb1 = (const float*)d_in[base + 5];
    const float* fw2 = (const float*)d_in[base + 6];
    const float* fb2 = (const float*)d_in[base + 7];
    const float* gw1 = (const float*)d_in[base + 8];
    const float* gb1 = (const float*)d_in[base + 9];
    const float* ggm = (const float*)d_in[base + 10];
    const float* gbt = (const float*)d_in[base + 11];
    const float* gw2 = (const float*)d_in[base + 12];
    const float* gb2 = (const float*)d_in[base + 13];

    k_delta_q<<<NB_NODE, 256, 0, stream>>>(x, pos, hw1, hb1, hw2, hb2, q);
    k_xa<<<NB_NODE, 256, 0, stream>>>(x, fw1, fb1, xa, agg);
    k_edge<<<NB_EDGE, 256, 0, stream>>>(xa, pos, q, ei, fw1, fb2, fw2, agg);
    float* g = xa;  // xa dead after k_edge; reuse as g
    k_g_bn<<<NBLK_BN, 256, 0, stream>>>(agg, gw1, gb1, g, bnp);
    k_bn_final<<<1, 128, 0, stream>>>(bnp, ggm, gbt, gw2, gb2, w2p, b2p, NBLK_BN);
    k_update<<<NB_NODE, 256, 0, stream>>>(g, w2p, b2p, x);
  }

  k_pool<<<NG, 512, 0, stream>>>(x, batch, pooled);
  k_readout<<<NG, 64, 0, stream>>>(pooled, ro_w1, ro_b1, ro_w2, ro_b2, out);
}

// Round 6
// 1372.891 us; speedup vs baseline: 1.4799x; 1.1549x over previous
//
#include <hip/hip_runtime.h>

#define NN 100000
#define NE 1600000
#define NG 64
#define EPS 1e-5f
#define SCAN_NB 98  // ceil(NN/1024)

// ---------- macro machinery: 16 named float4 regs = one 64-row weight column ----------
// Named scalars + asm pin: compiler can neither scratch-demote (rule #20) nor
// rematerialize-from-global (round-4 pathology: k_edge VGPR=40 => weights reloaded
// from L1 every edge). The asm output is opaque, so values MUST stay live in VGPRs.
#define FOR16(M) M(0) M(1) M(2) M(3) M(4) M(5) M(6) M(7) M(8) M(9) M(10) M(11) M(12) M(13) M(14) M(15)

#define WDECL(i) float4 wr##i##_;
#define LDW(i, RB, P) \
  wr##i##_.x = (P)[((RB) + 4 * i + 0) * 64 + lane]; \
  wr##i##_.y = (P)[((RB) + 4 * i + 1) * 64 + lane]; \
  wr##i##_.z = (P)[((RB) + 4 * i + 2) * 64 + lane]; \
  wr##i##_.w = (P)[((RB) + 4 * i + 3) * 64 + lane];
#define WPIN(i) asm volatile("" : "+v"(wr##i##_.x), "+v"(wr##i##_.y), "+v"(wr##i##_.z), "+v"(wr##i##_.w));
#define DOTR(i) { float4 v = xr[i]; \
  a0 = fmaf(v.x, wr##i##_.x, a0); a1 = fmaf(v.y, wr##i##_.y, a1); \
  a2 = fmaf(v.z, wr##i##_.z, a2); a3 = fmaf(v.w, wr##i##_.w, a3); }
#define DOTB(i, SRC) { \
  a0 = fmaf(bcast(SRC, 4 * i + 0), wr##i##_.x, a0); \
  a1 = fmaf(bcast(SRC, 4 * i + 1), wr##i##_.y, a1); \
  a2 = fmaf(bcast(SRC, 4 * i + 2), wr##i##_.z, a2); \
  a3 = fmaf(bcast(SRC, 4 * i + 3), wr##i##_.w, a3); }

// second register set (for the fused node kernel holding two weight matrices)
#define BDECL(i) float4 br##i##_;
#define LDB(i, RB, P) \
  br##i##_.x = (P)[((RB) + 4 * i + 0) * 64 + lane]; \
  br##i##_.y = (P)[((RB) + 4 * i + 1) * 64 + lane]; \
  br##i##_.z = (P)[((RB) + 4 * i + 2) * 64 + lane]; \
  br##i##_.w = (P)[((RB) + 4 * i + 3) * 64 + lane];
#define BPIN(i) asm volatile("" : "+v"(br##i##_.x), "+v"(br##i##_.y), "+v"(br##i##_.z), "+v"(br##i##_.w));
#define DOTRB(i) { float4 v = xr[i]; \
  a0 = fmaf(v.x, br##i##_.x, a0); a1 = fmaf(v.y, br##i##_.y, a1); \
  a2 = fmaf(v.z, br##i##_.z, a2); a3 = fmaf(v.w, br##i##_.w, a3); }

// ---------- helpers ----------
__device__ __forceinline__ int wave_gid() {
  return __builtin_amdgcn_readfirstlane((int)((blockIdx.x * blockDim.x + threadIdx.x) >> 6));
}

__device__ __forceinline__ float bcast(float v, int l) {
  return __uint_as_float(__builtin_amdgcn_readlane(__float_as_uint(v), l));
}

__device__ __forceinline__ void graph_range(const int* __restrict__ batch, int g, int& s, int& e) {
  int a = 0, b = NN;
  while (a < b) { int m = (a + b) >> 1; if (batch[m] < g) a = m + 1; else b = m; }
  s = a;
  b = NN;
  while (a < b) { int m = (a + b) >> 1; if (batch[m] < g + 1) a = m + 1; else b = m; }
  e = a;
}

// ---------- CSR build: hist -> scan -> scatter (dst-bucketed, order-free) ----------
__global__ void k_zero(unsigned* __restrict__ hist, float* __restrict__ psum) {
  int i = blockIdx.x * blockDim.x + threadIdx.x;
  int st = gridDim.x * blockDim.x;
  for (int j = i; j < NN; j += st) hist[j] = 0u;
  for (int j = i; j < NG * 64; j += st) psum[j] = 0.f;
}

__global__ void k_hist(const int* __restrict__ ei, unsigned* __restrict__ hist) {
  int i = blockIdx.x * blockDim.x + threadIdx.x;
  int st = gridDim.x * blockDim.x;
  for (int e = i; e < NE; e += st) atomicAdd(&hist[ei[NE + e]], 1u);
}

__global__ void k_scan1(const unsigned* __restrict__ hist, unsigned* __restrict__ coff,
                        unsigned* __restrict__ bsum) {
  __shared__ unsigned sd[256];
  int t = threadIdx.x;
  int base = blockIdx.x * 1024 + t * 4;
  unsigned v0 = (base + 0 < NN) ? hist[base + 0] : 0u;
  unsigned v1 = (base + 1 < NN) ? hist[base + 1] : 0u;
  unsigned v2 = (base + 2 < NN) ? hist[base + 2] : 0u;
  unsigned v3 = (base + 3 < NN) ? hist[base + 3] : 0u;
  unsigned tsum = v0 + v1 + v2 + v3;
  sd[t] = tsum;
  __syncthreads();
  for (int off = 1; off < 256; off <<= 1) {
    unsigned add = (t >= off) ? sd[t - off] : 0u;
    __syncthreads();
    sd[t] += add;
    __syncthreads();
  }
  unsigned p = sd[t] - tsum;  // exclusive prefix of this thread within block
  if (t == 255) bsum[blockIdx.x] = sd[255];
  if (base + 0 < NN) coff[base + 0] = p; p += v0;
  if (base + 1 < NN) coff[base + 1] = p; p += v1;
  if (base + 2 < NN) coff[base + 2] = p; p += v2;
  if (base + 3 < NN) coff[base + 3] = p;
}

__global__ void k_scan2(unsigned* __restrict__ bsum) {
  __shared__ unsigned sd[128];
  int t = threadIdx.x;
  unsigned v = (t < SCAN_NB) ? bsum[t] : 0u;
  sd[t] = v;
  __syncthreads();
  for (int off = 1; off < 128; off <<= 1) {
    unsigned add = (t >= off) ? sd[t - off] : 0u;
    __syncthreads();
    sd[t] += add;
    __syncthreads();
  }
  if (t < SCAN_NB) bsum[t] = sd[t] - v;  // exclusive
}

__global__ void k_scan3(unsigned* __restrict__ coff, const unsigned* __restrict__ bsum,
                        unsigned* __restrict__ cursor) {
  int i = blockIdx.x * blockDim.x + threadIdx.x;
  if (i < NN) {
    unsigned v = coff[i] + bsum[i >> 10];
    coff[i] = v;
    cursor[i] = v;
  }
  if (i == 0) coff[NN] = NE;
}

__global__ void k_scatter(const int* __restrict__ ei, unsigned* __restrict__ cursor,
                          int* __restrict__ csrc) {
  int i = blockIdx.x * blockDim.x + threadIdx.x;
  int st = gridDim.x * blockDim.x;
  for (int e = i; e < NE; e += st) {
    int dst = ei[NE + e];
    unsigned p = atomicAdd(&cursor[dst], 1u);
    csrc[p] = ei[e];
  }
}

// ---------- K0: x = h @ fe_w + fe_b ----------
__global__ void __launch_bounds__(256) k_init_x(const float* __restrict__ h,
                                                const float* __restrict__ few,
                                                const float* __restrict__ feb,
                                                float* __restrict__ x) {
  int lane = threadIdx.x & 63;
  int wg = wave_gid();
  int nw = (gridDim.x * blockDim.x) >> 6;
  float c0 = few[0 * 64 + lane], c1 = few[1 * 64 + lane];
  float c2 = few[2 * 64 + lane], c3 = few[3 * 64 + lane];
  float b = feb[lane];
  for (int n = wg; n < NN; n += nw) {
    float4 hv = *(const float4*)(h + (size_t)n * 4);
    x[(size_t)n * 64 + lane] = fmaf(hv.x, c0, fmaf(hv.y, c1, fmaf(hv.z, c2, fmaf(hv.w, c3, b))));
  }
}

// ---------- K1: fused node pre-pass: q = pos - delta(x),  xa = x @ fw1[3:] + fb1 ----------
__global__ void __launch_bounds__(256) k_node_pre(
    const float* __restrict__ x, const float* __restrict__ pos,
    const float* __restrict__ hw1, const float* __restrict__ hb1,
    const float* __restrict__ hw2, const float* __restrict__ hb2,
    const float* __restrict__ fw1, const float* __restrict__ fb1,
    float* __restrict__ q, float* __restrict__ xa) {
  int lane = threadIdx.x & 63;
  int wg = wave_gid();
  int nw = (gridDim.x * blockDim.x) >> 6;
  FOR16(WDECL)
  FOR16(BDECL)
#define LD(i) LDW(i, 0, hw1)
  FOR16(LD)
#undef LD
#define LD(i) LDB(i, 3, fw1)
  FOR16(LD)
#undef LD
  FOR16(WPIN)
  FOR16(BPIN)
  float b1 = hb1[lane];
  float fb = fb1[lane];
  float u0 = hw2[lane * 3 + 0], u1 = hw2[lane * 3 + 1], u2 = hw2[lane * 3 + 2];
  float b20 = hb2[0], b21 = hb2[1], b22 = hb2[2];
  for (int n = wg; n < NN; n += nw) {
    const float4* xr = (const float4*)(x + (size_t)n * 64);
    float a0 = 0.f, a1 = 0.f, a2 = 0.f, a3 = 0.f;
    FOR16(DOTR)
    float t = fmaxf((a0 + a1) + (a2 + a3) + b1, 0.f);
    float p0 = t * u0, p1 = t * u1, p2 = t * u2;
#pragma unroll
    for (int off = 32; off; off >>= 1) {
      p0 += __shfl_xor(p0, off);
      p1 += __shfl_xor(p1, off);
      p2 += __shfl_xor(p2, off);
    }
    a0 = 0.f; a1 = 0.f; a2 = 0.f; a3 = 0.f;
    FOR16(DOTRB)
    xa[(size_t)n * 64 + lane] = (a0 + a1) + (a2 + a3) + fb;
    if (lane < 3) {
      float dc = (lane == 0) ? (p0 + b20) : ((lane == 1) ? (p1 + b21) : (p2 + b22));
      q[(size_t)n * 4 + lane] = pos[(size_t)n * 3 + lane] - dc;
    }
  }
}

// ---------- K3: edge kernel, CSR form — one wave per dst, register max, no atomics ----------
__global__ void __launch_bounds__(256) k_edge_csr(
    const float* __restrict__ xa, const float* __restrict__ pos,
    const float* __restrict__ q, const unsigned* __restrict__ coff,
    const int* __restrict__ csrc, const float* __restrict__ fw1,
    const float* __restrict__ fb2_, const float* __restrict__ fw2,
    float* __restrict__ agg) {
  int lane = threadIdx.x & 63;
  int wg = wave_gid();
  int nw = (gridDim.x * blockDim.x) >> 6;
  FOR16(WDECL)
#define LD(i) LDW(i, 0, fw2)
  FOR16(LD)
#undef LD
  FOR16(WPIN)
  float pw0 = fw1[0 * 64 + lane], pw1 = fw1[1 * 64 + lane], pw2 = fw1[2 * 64 + lane];
  float bl = fb2_[lane];
  const float NEGINF = __int_as_float(0xff800000);
  for (int dst = wg; dst < NN; dst += nw) {
    unsigned s = coff[dst], e = coff[dst + 1];
    float4 qd = *(const float4*)(q + (size_t)dst * 4);
    float mx = NEGINF;
    if (e > s) {
      // software-pipelined: prefetch next edge's src/pos/xa under current DOTB
      int src = csrc[s];
      float px = pos[(size_t)src * 3 + 0];
      float py = pos[(size_t)src * 3 + 1];
      float pz = pos[(size_t)src * 3 + 2];
      float hh = xa[(size_t)src * 64 + lane];
      for (unsigned i = s; i < e; ++i) {
        float cpx = px, cpy = py, cpz = pz, chh = hh;
        if (i + 1 < e) {
          int ns = csrc[i + 1];
          px = pos[(size_t)ns * 3 + 0];
          py = pos[(size_t)ns * 3 + 1];
          pz = pos[(size_t)ns * 3 + 2];
          hh = xa[(size_t)ns * 64 + lane];
        }
        float rx = cpx - qd.x, ry = cpy - qd.y, rz = cpz - qd.z;
        float pre = fmaxf(fmaf(rx, pw0, fmaf(ry, pw1, fmaf(rz, pw2, chh))), 0.f);
        float a0 = bl, a1 = 0.f, a2 = 0.f, a3 = 0.f;
#define DB(i) DOTB(i, pre)
        FOR16(DB)
#undef DB
        mx = fmaxf(mx, (a0 + a1) + (a2 + a3));
      }
    }
    agg[(size_t)dst * 64 + lane] = (e > s) ? mx : 0.f;  // empty segment -> 0
  }
}

// ---------- K4: g = relu(agg @ gw1 + gb1), BN partial sums ----------
__global__ void __launch_bounds__(256) k_g_bn(
    const float* __restrict__ agg, const float* __restrict__ gw1,
    const float* __restrict__ gb1, float* __restrict__ g, float* __restrict__ bnp) {
  __shared__ float2 red[4][64];
  int lane = threadIdx.x & 63;
  int wid = threadIdx.x >> 6;
  int wg = wave_gid();
  int nw = (gridDim.x * blockDim.x) >> 6;
  FOR16(WDECL)
#define LD(i) LDW(i, 0, gw1)
  FOR16(LD)
#undef LD
  FOR16(WPIN)
  float b = gb1[lane];
  float s = 0.f, ss = 0.f;
  for (int n = wg; n < NN; n += nw) {
    float av = agg[(size_t)n * 64 + lane];
    float a0 = 0.f, a1 = 0.f, a2 = 0.f, a3 = 0.f;
#define DB(i) DOTB(i, av)
    FOR16(DB)
#undef DB
    float gv = fmaxf((a0 + a1) + (a2 + a3) + b, 0.f);
    g[(size_t)n * 64 + lane] = gv;
    s += gv;
    ss += gv * gv;
  }
  red[wid][lane] = make_float2(s, ss);
  __syncthreads();
  if (wid == 0) {
    float2 r0 = red[0][lane], r1 = red[1][lane], r2 = red[2][lane], r3 = red[3][lane];
    bnp[(size_t)blockIdx.x * 128 + lane] = r0.x + r1.x + r2.x + r3.x;
    bnp[(size_t)blockIdx.x * 128 + 64 + lane] = r0.y + r1.y + r2.y + r3.y;
  }
}

// ---------- K5: finalize BN, fold into W2', b2' ----------
#define NBLK_BN 256
__global__ void k_bn_final(const float* __restrict__ bnp, const float* __restrict__ gm,
                           const float* __restrict__ bt, const float* __restrict__ gw2,
                           const float* __restrict__ gb2, float* __restrict__ w2p,
                           float* __restrict__ b2p) {
  __shared__ float sums[128];
  __shared__ float sc[64], sh[64];
  int t = threadIdx.x;  // 128 threads
  int c = t & 63;
  int kind = t >> 6;
  float acc = 0.f;
#pragma unroll 8
  for (int bId = 0; bId < NBLK_BN; ++bId) acc += bnp[(size_t)bId * 128 + kind * 64 + c];
  sums[t] = acc;
  __syncthreads();
  if (t < 64) {
    float mean = sums[t] * (1.f / (float)NN);
    float var = sums[64 + t] * (1.f / (float)NN) - mean * mean;
    float scale = gm[t] * rsqrtf(var + EPS);
    sc[t] = scale;
    sh[t] = bt[t] - mean * scale;
  }
  __syncthreads();
  for (int i = t; i < 4096; i += 128) {
    int d = i >> 6;
    w2p[i] = sc[d] * gw2[i];
  }
  if (t < 64) {
    float acc2 = gb2[t];
#pragma unroll 8
    for (int d = 0; d < 64; ++d) acc2 = fmaf(sh[d], gw2[d * 64 + t], acc2);
    b2p[t] = acc2;
  }
}

// ---------- K6: x += g @ W2' + b2' ----------
__global__ void __launch_bounds__(256) k_update(
    const float* __restrict__ g, const float* __restrict__ w2p,
    const float* __restrict__ b2p, float* __restrict__ x) {
  int lane = threadIdx.x & 63;
  int wg = wave_gid();
  int nw = (gridDim.x * blockDim.x) >> 6;
  FOR16(WDECL)
#define LD(i) LDW(i, 0, w2p)
  FOR16(LD)
#undef LD
  FOR16(WPIN)
  float b = b2p[lane];
  for (int n = wg; n < NN; n += nw) {
    const float4* xr = (const float4*)(g + (size_t)n * 64);
    float a0 = 0.f, a1 = 0.f, a2 = 0.f, a3 = 0.f;
    FOR16(DOTR)
    size_t idx = (size_t)n * 64 + lane;
    x[idx] = x[idx] + (a0 + a1) + (a2 + a3) + b;
  }
}

// ---------- K7: pool partials — 4 blocks/graph, float atomics into psum ----------
__global__ void __launch_bounds__(512) k_pool_partial(const float* __restrict__ x,
                                                      const int* __restrict__ batch,
                                                      float* __restrict__ psum) {
  __shared__ float red[8][64];
  int lane = threadIdx.x & 63;
  int wid = threadIdx.x >> 6;  // 0..7
  int g = blockIdx.x >> 2;
  int part = blockIdx.x & 3;
  int s, e;
  graph_range(batch, g, s, e);
  float acc = 0.f;
  for (int n = s + part * 8 + wid; n < e; n += 32) acc += x[(size_t)n * 64 + lane];
  red[wid][lane] = acc;
  __syncthreads();
  if (wid == 0) {
    float t = acc;
#pragma unroll
    for (int w = 1; w < 8; ++w) t += red[w][lane];
    atomicAdd(&psum[(size_t)g * 64 + lane], t);
  }
}

// ---------- K8: readout MLP (divide-by-count folded into the dot) ----------
__global__ void __launch_bounds__(64) k_readout(
    const float* __restrict__ psum, const int* __restrict__ batch,
    const float* __restrict__ w1, const float* __restrict__ b1,
    const float* __restrict__ w2, const float* __restrict__ b2,
    float* __restrict__ out) {
  __shared__ float hs[64];
  int lane = threadIdx.x;  // 64 threads, 1 block per graph
  int g = blockIdx.x;
  int s, e;
  graph_range(batch, g, s, e);
  float scale = 1.f / fmaxf((float)(e - s), 1.f);
  FOR16(WDECL)
#define LD(i) LDW(i, 0, w1)
  FOR16(LD)
#undef LD
  const float4* xr = (const float4*)(psum + (size_t)g * 64);
  float a0 = 0.f, a1 = 0.f, a2 = 0.f, a3 = 0.f;
  FOR16(DOTR)
  hs[lane] = fmaxf(((a0 + a1) + (a2 + a3)) * scale + b1[lane], 0.f);
  __syncthreads();
  if (lane < 16) {
    float acc = b2[lane];
#pragma unroll
    for (int l = 0; l < 64; ++l) acc = fmaf(hs[l], w2[l * 16 + lane], acc);
    out[(size_t)g * 16 + lane] = acc;
  }
}

// ---------- host ----------
extern "C" void kernel_launch(void* const* d_in, const int* in_sizes, int n_in,
                              void* d_out, int out_size, void* d_ws, size_t ws_size,
                              hipStream_t stream) {
  const float* h = (const float*)d_in[0];
  const float* pos = (const float*)d_in[1];
  const int* ei = (const int*)d_in[2];
  const int* batch = (const int*)d_in[3];
  const float* fe_w = (const float*)d_in[4];
  const float* fe_b = (const float*)d_in[5];
  const float* ro_w1 = (const float*)d_in[34];
  const float* ro_b1 = (const float*)d_in[35];
  const float* ro_w2 = (const float*)d_in[36];
  const float* ro_b2 = (const float*)d_in[37];
  float* out = (float*)d_out;

  char* ws = (char*)d_ws;
  const size_t SZ_ROW = (size_t)NN * 64 * sizeof(float);  // 25.6 MB
  float* x = (float*)(ws); ws += SZ_ROW;
  float* xa = (float*)(ws); ws += SZ_ROW;                  // reused as g after edge phase
  float* agg = (float*)(ws); ws += SZ_ROW;
  float* q = (float*)(ws); ws += (size_t)NN * 4 * sizeof(float);
  float* bnp = (float*)(ws); ws += (size_t)NBLK_BN * 128 * sizeof(float);
  float* w2p = (float*)(ws); ws += 4096 * sizeof(float);
  float* b2p = (float*)(ws); ws += 256;
  float* psum = (float*)(ws); ws += (size_t)NG * 64 * sizeof(float);
  unsigned* cursor = (unsigned*)(ws); ws += ((size_t)NN * 4 + 256);   // doubles as hist
  unsigned* coff = (unsigned*)(ws); ws += ((size_t)(NN + 1) * 4 + 252);
  unsigned* bsum = (unsigned*)(ws); ws += 512;
  int* csrc = (int*)(ws); ws += (size_t)NE * 4;

  const int NB_NODE = 512;
  const int NB_EDGE = 4096;

  // CSR build (once — same graph for both convs)
  k_zero<<<256, 256, 0, stream>>>(cursor, psum);
  k_hist<<<1024, 256, 0, stream>>>(ei, cursor);
  k_scan1<<<SCAN_NB, 256, 0, stream>>>(cursor, coff, bsum);
  k_scan2<<<1, 128, 0, stream>>>(bsum);
  k_scan3<<<392, 256, 0, stream>>>(coff, bsum, cursor);
  k_scatter<<<1024, 256, 0, stream>>>(ei, cursor, csrc);

  k_init_x<<<NB_NODE, 256, 0, stream>>>(h, fe_w, fe_b, x);

  for (int layer = 0; layer < 2; ++layer) {
    int base = (layer == 0) ? 6 : 20;
    const float* hw1 = (const float*)d_in[base + 0];
    const float* hb1 = (const float*)d_in[base + 1];
    const float* hw2 = (const float*)d_in[base + 2];
    const float* hb2 = (const float*)d_in[base + 3];
    const float* fw1 = (const float*)d_in[base + 4];
    const float* fb1 = (const float*)d_in[base + 5];
    const float* fw2 = (const float*)d_in[base + 6];
    const float* fb2 = (const float*)d_in[base + 7];
    const float* gw1 = (const float*)d_in[base + 8];
    const float* gb1 = (const float*)d_in[base + 9];
    const float* ggm = (const float*)d_in[base + 10];
    const float* gbt = (const float*)d_in[base + 11];
    const float* gw2 = (const float*)d_in[base + 12];
    const float* gb2 = (const float*)d_in[base + 13];

    k_node_pre<<<NB_NODE, 256, 0, stream>>>(x, pos, hw1, hb1, hw2, hb2, fw1, fb1, q, xa);
    k_edge_csr<<<NB_EDGE, 256, 0, stream>>>(xa, pos, q, coff, csrc, fw1, fb2, fw2, agg);
    float* g = xa;  // xa dead after k_edge_csr; reuse as g
    k_g_bn<<<NBLK_BN, 256, 0, stream>>>(agg, gw1, gb1, g, bnp);
    k_bn_final<<<1, 128, 0, stream>>>(bnp, ggm, gbt, gw2, gb2, w2p, b2p);
    k_update<<<NB_NODE, 256, 0, stream>>>(g, w2p, b2p, x);
  }

  k_pool_partial<<<NG * 4, 512, 0, stream>>>(x, batch, psum);
  k_readout<<<NG, 64, 0, stream>>>(psum, batch, ro_w1, ro_b1, ro_w2, ro_b2, out);
}